// Round 19
// baseline (54.656 us; speedup 1.0000x reference)
//
#include <hip/hip_runtime.h>
#include <cmath>

// SDYUnit: per-pixel conv chain via 32x32x16 fp16 MFMA.
// R19 = R18 + TWO independent 64-pixel batches per wave (R7 redux -- now
// register-feasible under the slim fp16 scheme). Measured residency is
// pinned at ~2.2 waves/SIMD across 5 geometries, so ~50% of issue slots are
// dependency-stall bubbles; the sibling batch's independent MFMA chain
// fills them. __launch_bounds__(512,2): 256-reg cap, no spill (~200 live).
// Single fp16 weights (RNE) + fp16 activations (RTZ).
// Weight k-columns pre-permuted so packed accumulators ARE the next layer's
// B operand: B-slot (h,j) of K-step ks <-> k' = (j&3) + 8*(2ks+(j>>2)) + 4h.

static constexpr int Hh = 190, Ww = 190, Him = 192, Wim = 192, Nimg = 24;
static constexpr int NPIX = Nimg * Hh * Ww;        // 866,400
static constexpr int NWG  = (NPIX + 1023) / 1024;  // 847

typedef __attribute__((ext_vector_type(8)))  _Float16 half8v;  // 8 fp16 (4 VGPR)
typedef __attribute__((ext_vector_type(16))) float f32x16;     // C/D frag
typedef __attribute__((ext_vector_type(4)))  unsigned int uint4v;

// fragment indices in ws (each frag = 512 shorts = 1024 B = 64 uint4v)
static constexpr int FR_L1  = 0;    // +mt  (2 frags)
static constexpr int FR_L6  = 2;    // +ks  (4 frags)
static constexpr int FR_MID = 6;    // +(L*8 + mt*4 + ks)  (32 frags)
// compressed bias tables (floats; after 38 frags = 19456 shorts = 9728 f32)
static constexpr int BT_BASE = 9728;  // [0,256) mid [L][mt][b5][16]
                                      // [256,320) L1 [mt][b5][16]
                                      // [320,352) L6 [b5][16]

__global__ __launch_bounds__(256) void prep_kernel(
    const float* __restrict__ W1, const float* __restrict__ W2,
    const float* __restrict__ W3, const float* __restrict__ W4,
    const float* __restrict__ W5, const float* __restrict__ W6,
    const float* __restrict__ b1, const float* __restrict__ b2,
    const float* __restrict__ b3, const float* __restrict__ b4,
    const float* __restrict__ b5, const float* __restrict__ b6,
    short* __restrict__ ws) {
  float* wsF = (float*)ws;
  int t0 = blockIdx.x * 256 + threadIdx.x;
  int stride = gridDim.x * 256;
  // mid layers: A[row][k'], row = mt*32+(lane&31), k' per permuted slot map
  for (int idx = t0; idx < 32 * 512; idx += stride) {
    int j = idx & 7, lane = (idx >> 3) & 63, fi = idx >> 9;
    int ks = fi & 3, mt = (fi >> 2) & 1, L = fi >> 3;
    const float* W = (L == 0) ? W2 : (L == 1) ? W3 : (L == 2) ? W4 : W5;
    int g = mt * 32 + (lane & 31);
    int k = (j & 3) + 8 * (2 * ks + (j >> 2)) + 4 * (lane >> 5);
    _Float16 h = (_Float16)W[g * 64 + k];
    ws[(FR_MID + fi) * 512 + (idx & 511)] = __builtin_bit_cast(short, h);
  }
  // layer 1: taps in slots j=0..3 of BOTH halves (B zeroes the non-owner half)
  for (int idx = t0; idx < 2 * 512; idx += stride) {
    int j = idx & 7, lane = (idx >> 3) & 63, mt = idx >> 9;
    int g = mt * 32 + (lane & 31);
    float w = (j < 4) ? W1[g * 4 + j] : 0.f;
    _Float16 h = (_Float16)w;
    ws[(FR_L1 + mt) * 512 + (idx & 511)] = __builtin_bit_cast(short, h);
  }
  // layer 6: M=16 zero-padded to 32, same permuted k map
  for (int idx = t0; idx < 4 * 512; idx += stride) {
    int j = idx & 7, lane = (idx >> 3) & 63, ks = idx >> 9;
    int g = lane & 31;
    int k = (j & 3) + 8 * (2 * ks + (j >> 2)) + 4 * (lane >> 5);
    float w = (g < 16) ? W6[g * 64 + k] : 0.f;
    _Float16 h = (_Float16)w;
    ws[(FR_L6 + ks) * 512 + (idx & 511)] = __builtin_bit_cast(short, h);
  }
  // compressed bias tables: C/D reg r of lane-half b5 = row (r>>2)*8+b5*4+(r&3)
  for (int idx = t0; idx < 256; idx += stride) {   // mid [L][mt][b5][16]
    int r = idx & 15, b5v = (idx >> 4) & 1, mt = (idx >> 5) & 1, L = idx >> 6;
    const float* bb = (L == 0) ? b2 : (L == 1) ? b3 : (L == 2) ? b4 : b5;
    wsF[BT_BASE + idx] = bb[mt * 32 + (r >> 2) * 8 + b5v * 4 + (r & 3)];
  }
  for (int idx = t0; idx < 64; idx += stride) {    // L1 [mt][b5][16]
    int r = idx & 15, b5v = (idx >> 4) & 1, mt = idx >> 5;
    wsF[BT_BASE + 256 + idx] = b1[mt * 32 + (r >> 2) * 8 + b5v * 4 + (r & 3)];
  }
  for (int idx = t0; idx < 32; idx += stride) {    // L6 [b5][16] (rows>=8 zero)
    int r = idx & 15, b5v = idx >> 4;
    wsF[BT_BASE + 320 + idx] = (r < 8) ? b6[(r >> 2) * 8 + b5v * 4 + (r & 3)] : 0.f;
  }
}

// ---------------- device helpers ----------------

// packed fp16 pair, RTZ, one instruction (dst.lo = a, dst.hi = b)
__device__ __forceinline__ unsigned pkrtz(float a, float b) {
  unsigned r;
  asm("v_cvt_pkrtz_f16_f32 %0, %1, %2" : "=v"(r) : "v"(a), "v"(b));
  return r;
}

__device__ __forceinline__ half8v mkfrag(unsigned a0, unsigned a1,
                                         unsigned b0, unsigned b1) {
  uint4v u = {a0, a1, b0, b1};
  return __builtin_bit_cast(half8v, u);
}

// relu (f32 fmax) + RTZ-pack one 16-value acc tile -> two B-frag halves [s].
__device__ __forceinline__ void epi_tile(const f32x16& acc, half8v (&o)[2]) {
#pragma unroll
  for (int s = 0; s < 2; ++s) {
    unsigned h[4];
#pragma unroll
    for (int d = 0; d < 4; ++d) {
      float v0 = fmaxf(acc[8 * s + 2 * d + 0], 0.f);
      float v1 = fmaxf(acc[8 * s + 2 * d + 1], 0.f);
      h[d] = pkrtz(v0, v1);
    }
    o[s] = mkfrag(h[0], h[1], h[2], h[3]);
  }
}

// one 64->64 layer for BOTH batches; frag arrays indexed [b][ms][nt][s].
// Per (mt,nt) tile the two batches' MFMA chains are interleaved -> in-wave ILP.
__device__ __forceinline__ void mid_layer2(const short* wlds, const float* bt,
    int Lbase, int lane, int b5,
    half8v (&fo)[2][2][2][2], half8v (&fn)[2][2][2][2]) {
#pragma unroll
  for (int mt = 0; mt < 2; ++mt) {
    const short* wb = wlds + (Lbase + mt * 4) * 512 + lane * 8;
    half8v a0 = *(const half8v*)(wb + 0 * 512);
    half8v a1 = *(const half8v*)(wb + 1 * 512);
    half8v a2 = *(const half8v*)(wb + 2 * 512);
    half8v a3 = *(const half8v*)(wb + 3 * 512);
    f32x16 bf = *(const f32x16*)(bt + (mt * 2 + b5) * 16);
#pragma unroll
    for (int nt = 0; nt < 2; ++nt) {
      f32x16 acc0, acc1;   // interleaved independent chains
      acc0 = __builtin_amdgcn_mfma_f32_32x32x16_f16(a0, fo[0][0][nt][0], bf, 0, 0, 0);
      acc1 = __builtin_amdgcn_mfma_f32_32x32x16_f16(a0, fo[1][0][nt][0], bf, 0, 0, 0);
      acc0 = __builtin_amdgcn_mfma_f32_32x32x16_f16(a1, fo[0][0][nt][1], acc0, 0, 0, 0);
      acc1 = __builtin_amdgcn_mfma_f32_32x32x16_f16(a1, fo[1][0][nt][1], acc1, 0, 0, 0);
      acc0 = __builtin_amdgcn_mfma_f32_32x32x16_f16(a2, fo[0][1][nt][0], acc0, 0, 0, 0);
      acc1 = __builtin_amdgcn_mfma_f32_32x32x16_f16(a2, fo[1][1][nt][0], acc1, 0, 0, 0);
      acc0 = __builtin_amdgcn_mfma_f32_32x32x16_f16(a3, fo[0][1][nt][1], acc0, 0, 0, 0);
      acc1 = __builtin_amdgcn_mfma_f32_32x32x16_f16(a3, fo[1][1][nt][1], acc1, 0, 0, 0);
      epi_tile(acc0, fn[0][mt][nt]);
      epi_tile(acc1, fn[1][mt][nt]);
    }
  }
}

__device__ __forceinline__ float ftanh(float x) {
  float e = __expf(2.0f * x);
  return 1.0f - __fdividef(2.0f, e + 1.0f);
}

__global__ __launch_bounds__(512, 2) void fused_kernel(
    const float* __restrict__ x, const short* __restrict__ ws,
    float* __restrict__ out) {
  __shared__ __align__(16) short wlds[16384];  // 32KB mid-layer weight frags
  __shared__ __align__(16) short wl16[3072];   // 6KB L1(2)+L6(4) frags
  __shared__ __align__(64) float blds[352];    // compressed bias tables

  const int lane = threadIdx.x & 63;
  const int wave = threadIdx.x >> 6;
  const int b5 = lane >> 5, lo5 = lane & 31;
  const int wgbase = blockIdx.x * 1024;

  // ---- hoisted x loads for both batches ----
  float t[2][4];
#pragma unroll
  for (int b = 0; b < 2; ++b) {
    int p = wgbase + b * 512 + wave * 64 + lane;
    int pc = p < NPIX ? p : NPIX - 1;
    unsigned jj = (unsigned)pc % 190u;
    unsigned r  = (unsigned)pc / 190u;
    unsigned ii = r % 190u, nn = r / 190u;
    const float* xp = x + ((nn * 192u + ii) * 192u + jj);
    t[b][0] = xp[0]; t[b][1] = xp[1]; t[b][2] = xp[192]; t[b][3] = xp[193];
  }

  // ---- stage weight frags + bias tables into LDS (R17-proven, 512 thr) ----
  {
    int tid = threadIdx.x;
    const uint4v* src = (const uint4v*)ws;
    if (tid < 384) ((uint4v*)wl16)[tid] = src[tid];
    uint4v* dstM = (uint4v*)wlds;
#pragma unroll
    for (int it = 0; it < 4; ++it)
      dstM[it * 512 + tid] = src[384 + it * 512 + tid];
    const float* wsF = (const float*)ws;
    if (tid < 352) blds[tid] = wsF[BT_BASE + tid];
  }
  __syncthreads();

  half8v fA[2][2][2][2], fB[2][2][2][2];   // [b][ms][nt][s] ping-pong

  // ---------------- layer 1 (K=4 padded, via MFMA) -> fA ----------------
  {
    half8v Bv[2][2];   // [b][nt]
#pragma unroll
    for (int b = 0; b < 2; ++b) {
      unsigned th0 = pkrtz(t[b][0], t[b][1]), th1 = pkrtz(t[b][2], t[b][3]);
      unsigned z = 0u;
      unsigned s0h0 = (b5 == 0) ? th0 : z, s0h1 = (b5 == 0) ? th1 : z;
      unsigned s1h0 = (b5 == 1) ? th0 : z, s1h1 = (b5 == 1) ? th1 : z;
      Bv[b][0] = mkfrag(s0h0, s0h1, s0h0, s0h1);
      Bv[b][1] = mkfrag(s1h0, s1h1, s1h0, s1h1);
    }
#pragma unroll
    for (int mt = 0; mt < 2; ++mt) {
      f32x16 bf = *(const f32x16*)(blds + 256 + (mt * 2 + b5) * 16);
      half8v a = *(const half8v*)(wl16 + (FR_L1 + mt) * 512 + lane * 8);
#pragma unroll
      for (int nt = 0; nt < 2; ++nt) {
        f32x16 acc0 = __builtin_amdgcn_mfma_f32_32x32x16_f16(a, Bv[0][nt], bf, 0, 0, 0);
        f32x16 acc1 = __builtin_amdgcn_mfma_f32_32x32x16_f16(a, Bv[1][nt], bf, 0, 0, 0);
        epi_tile(acc0, fA[0][mt][nt]);
        epi_tile(acc1, fA[1][mt][nt]);
      }
    }
  }

  // ---------------- layers 2..5 (ping-pong fA/fB) ----------------
  mid_layer2(wlds, blds + 0 * 64, 0,  lane, b5, fA, fB);
  mid_layer2(wlds, blds + 1 * 64, 8,  lane, b5, fB, fA);
  mid_layer2(wlds, blds + 2 * 64, 16, lane, b5, fA, fB);
  mid_layer2(wlds, blds + 3 * 64, 24, lane, b5, fB, fA);

  // ---------------- layer 6 (M=16 padded) + tanh + shuffle-store ----------------
  {
    f32x16 c6 = *(const f32x16*)(blds + 320 + b5 * 16);
    const short* wb = wl16 + FR_L6 * 512 + lane * 8;
    half8v a0 = *(const half8v*)(wb + 0 * 512);
    half8v a1 = *(const half8v*)(wb + 1 * 512);
    half8v a2 = *(const half8v*)(wb + 2 * 512);
    half8v a3 = *(const half8v*)(wb + 3 * 512);
#pragma unroll
    for (int b = 0; b < 2; ++b)
#pragma unroll
      for (int nt = 0; nt < 2; ++nt) {
        f32x16 a6;
        a6 = __builtin_amdgcn_mfma_f32_32x32x16_f16(a0, fA[b][0][nt][0], c6, 0, 0, 0);
        a6 = __builtin_amdgcn_mfma_f32_32x32x16_f16(a1, fA[b][0][nt][1], a6, 0, 0, 0);
        a6 = __builtin_amdgcn_mfma_f32_32x32x16_f16(a2, fA[b][1][nt][0], a6, 0, 0, 0);
        a6 = __builtin_amdgcn_mfma_f32_32x32x16_f16(a3, fA[b][1][nt][1], a6, 0, 0, 0);
        int p2 = wgbase + b * 512 + wave * 64 + nt * 32 + lo5;
        if (p2 < NPIX) {
          unsigned jj = (unsigned)p2 % 190u;
          unsigned r  = (unsigned)p2 / 190u;
          unsigned ii = r % 190u, nn = r / 190u;
          int base = (int)((nn * 760u + ii * 4u) * 760u + jj * 4u);
          float4 s0, s1;
          s0.x = ftanh(a6[0]); s0.y = ftanh(a6[1]);
          s0.z = ftanh(a6[2]); s0.w = ftanh(a6[3]);
          s1.x = ftanh(a6[4]); s1.y = ftanh(a6[5]);
          s1.z = ftanh(a6[6]); s1.w = ftanh(a6[7]);
          *reinterpret_cast<float4*>(out + base + b5 * 760) = s0;        // rows: di=b5
          *reinterpret_cast<float4*>(out + base + (2 + b5) * 760) = s1;  // rows: di=2+b5
        }
      }
  }
}

extern "C" void kernel_launch(void* const* d_in, const int* in_sizes, int n_in,
                              void* d_out, int out_size, void* d_ws, size_t ws_size,
                              hipStream_t stream) {
  const float* x  = (const float*)d_in[0];
  const float* W1 = (const float*)d_in[1];
  const float* b1 = (const float*)d_in[2];
  const float* W2 = (const float*)d_in[3];
  const float* b2 = (const float*)d_in[4];
  const float* W3 = (const float*)d_in[5];
  const float* b3 = (const float*)d_in[6];
  const float* W4 = (const float*)d_in[7];
  const float* b4 = (const float*)d_in[8];
  const float* W5 = (const float*)d_in[9];
  const float* b5 = (const float*)d_in[10];
  const float* W6 = (const float*)d_in[11];
  const float* b6 = (const float*)d_in[12];

  hipLaunchKernelGGL(prep_kernel, dim3(64), dim3(256), 0, stream,
                     W1, W2, W3, W4, W5, W6, b1, b2, b3, b4, b5, b6, (short*)d_ws);
  hipLaunchKernelGGL(fused_kernel, dim3(NWG), dim3(512), 0, stream,
                     x, (const short*)d_ws, (float*)d_out);
}